// Round 2
// baseline (188.258 us; speedup 1.0000x reference)
//
#include <hip/hip_runtime.h>
#include <hip/hip_bf16.h>

typedef __attribute__((ext_vector_type(8))) short short8;
typedef __attribute__((ext_vector_type(4))) float f32x4;

struct XPtrs { const float* p[17]; };

__device__ __forceinline__ unsigned short f2bf(float f) {
  unsigned u = __float_as_uint(f);
  return (unsigned short)((u + 0x7fffu + ((u >> 16) & 1u)) >> 16);  // RNE
}

// ---------------- pre-kernel: W fp32 -> bf16, fragment-packed into ws ----
// Per diag d: 2048 slots of 16 B. slot = sg*128 + n  (sg = s*4 + g)
// slot holds W[d][n][k] for k = sg*8 .. sg*8+7 as 8 bf16.
__global__ __launch_bounds__(1024) void convert_w_kernel(
    const float* __restrict__ W, unsigned short* __restrict__ ws) {
  const int tid = blockIdx.x * 1024 + threadIdx.x;  // 0 .. 17*2048-1
  const int d  = tid >> 11;
  const int s2 = tid & 2047;
  const int sg = s2 >> 7;     // 0..15
  const int n  = s2 & 127;
  const float* src = W + ((size_t)d * 128 + n) * 128 + sg * 8;
  float4 a = *(const float4*)(src);
  float4 b = *(const float4*)(src + 4);
  unsigned u0 = (unsigned)f2bf(a.x) | ((unsigned)f2bf(a.y) << 16);
  unsigned u1 = (unsigned)f2bf(a.z) | ((unsigned)f2bf(a.w) << 16);
  unsigned u2 = (unsigned)f2bf(b.x) | ((unsigned)f2bf(b.y) << 16);
  unsigned u3 = (unsigned)f2bf(b.z) | ((unsigned)f2bf(b.w) << 16);
  uint4 v = make_uint4(u0, u1, u2, u3);
  *(uint4*)(ws + (size_t)tid * 8) = v;   // coalesced 16B writes
}

// ---------------- main kernel ----------------
// One block = one diagonal d, 256 flat rows (2 sub-tiles of 128).
// Flat row f of diag d is contiguous row f of x_d (f = b*L + l).
// Per sub-tile: 4 waves x 32 rows; MFMA operands SWAPPED (A=W, B=X) so each
// lane's 4 acc regs are 4 consecutive couts of one batch row -> dwordx4 store.
__global__ __launch_bounds__(256, 4) void diag_linear_kernel(
    XPtrs xp, const unsigned short* __restrict__ wsrc,
    const float* __restrict__ bias, float* __restrict__ out) {
  // block -> (diag d, chunk)
  int bid = blockIdx.x;
  int d = 0, base = 0;
  for (int i = 0; i < 17; ++i) {
    int Li = 9 - ((i < 8) ? (8 - i) : (i - 8));
    int nb = 32 * Li;                       // blocks for diag i
    if (bid < base + nb) { d = i; break; }
    base += nb;
  }
  const int chunk = bid - base;
  const int L = 9 - ((d < 8) ? (8 - d) : (d - 8));
  const int start = (d > 8) ? (d - 8) : 0;
  const float* __restrict__ x = xp.p[d];

  const int t = threadIdx.x;
  const int lane = t & 63;
  const int wave = t >> 6;
  const int lr = lane & 15;
  const int lg = lane >> 4;

  __shared__ unsigned short wlds[2048 * 8];  // 32 KiB, slot-linear

  // ---- stage W[d] (bf16, pre-packed) via async global->LDS, 16B/lane ----
  {
    const unsigned short* gw = wsrc + (size_t)d * 16384;
    typedef const __attribute__((address_space(1))) unsigned int* gas_u32;
    typedef __attribute__((address_space(3))) unsigned int* las_u32;
#pragma unroll
    for (int i = 0; i < 8; ++i) {
      const int slotbase = (wave * 8 + i) * 64;
      __builtin_amdgcn_global_load_lds(
          (gas_u32)(const void*)(gw + (size_t)(slotbase + lane) * 8),
          (las_u32)(void*)(wlds + (size_t)slotbase * 8),
          16, 0, 0);
    }
  }

  const int m0 = chunk * 256;
  __syncthreads();   // drains vmcnt -> W resident in LDS

#pragma unroll
  for (int sub = 0; sub < 2; ++sub) {
    const int m0s = m0 + sub * 128 + wave * 32;

    // ---- load X fragments (B operand): rows m0s+mb*16+lr, k=s*32+lg*8 ----
    short8 xf[2][4];
#pragma unroll
    for (int mb = 0; mb < 2; ++mb) {
      const float* xr = x + (size_t)(m0s + mb * 16 + lr) * 128;
#pragma unroll
      for (int s = 0; s < 4; ++s) {
        float4 a0 = *(const float4*)(xr + s * 32 + lg * 8);
        float4 a1 = *(const float4*)(xr + s * 32 + lg * 8 + 4);
        short8 f;
        f[0] = (short)f2bf(a0.x); f[1] = (short)f2bf(a0.y);
        f[2] = (short)f2bf(a0.z); f[3] = (short)f2bf(a0.w);
        f[4] = (short)f2bf(a1.x); f[5] = (short)f2bf(a1.y);
        f[6] = (short)f2bf(a1.z); f[7] = (short)f2bf(a1.w);
        xf[mb][s] = f;
      }
    }

    f32x4 acc[8][2];
#pragma unroll
    for (int nb = 0; nb < 8; ++nb) {
      acc[nb][0] = (f32x4){0.f, 0.f, 0.f, 0.f};
      acc[nb][1] = (f32x4){0.f, 0.f, 0.f, 0.f};
    }

    // ---- MFMA: A = W frag (couts), B = X frag (batch rows) ----
#pragma unroll
    for (int s = 0; s < 4; ++s) {
#pragma unroll
      for (int nb = 0; nb < 8; ++nb) {
        short8 wf = *(const short8*)&wlds[(size_t)((s * 4 + lg) * 128 + nb * 16 + lr) * 8];
        acc[nb][0] = __builtin_amdgcn_mfma_f32_16x16x32_bf16(wf, xf[0][s], acc[nb][0], 0, 0, 0);
        acc[nb][1] = __builtin_amdgcn_mfma_f32_16x16x32_bf16(wf, xf[1][s], acc[nb][1], 0, 0, 0);
      }
    }

    // ---- epilogue: D[cout = nb*16+lg*4+v][brow = mb*16+lr] ----
#pragma unroll
    for (int mb = 0; mb < 2; ++mb) {
      const int f = m0s + mb * 16 + lr;
      const unsigned b = (unsigned)f / (unsigned)L;
      const int l = f - (int)b * L;
      float* orow = out + (size_t)b * 10368 + (size_t)(start * 8 + d) * 128
                    + (size_t)l * 1024 + lg * 4;
#pragma unroll
      for (int nb = 0; nb < 8; ++nb) {
        f32x4 bv = *(const f32x4*)(bias + d * 128 + nb * 16 + lg * 4);
        f32x4 v = acc[nb][mb] + bv;
        __builtin_nontemporal_store(v, (f32x4*)(orow + nb * 16));
      }
    }
  }
}

extern "C" void kernel_launch(void* const* d_in, const int* in_sizes, int n_in,
                              void* d_out, int out_size, void* d_ws, size_t ws_size,
                              hipStream_t stream) {
  const float* W = (const float*)d_in[0];
  const float* bias = (const float*)d_in[1];
  XPtrs xp;
  for (int i = 0; i < 17; ++i) xp.p[i] = (const float*)d_in[2 + i];
  float* out = (float*)d_out;
  unsigned short* ws = (unsigned short*)d_ws;   // 17*2048*16 B = 544 KiB

  convert_w_kernel<<<34, 1024, 0, stream>>>(W, ws);
  diag_linear_kernel<<<2592, 256, 0, stream>>>(xp, ws, bias, out);
}